// Round 9
// baseline (449.188 us; speedup 1.0000x reference)
//
#include <hip/hip_runtime.h>
#include <cmath>

#define BB 8
#define NN 2048
#define CC 512
#define HH 8
#define DD 64
#define FF 1536
#define MM (BB*NN)   // 16384
#define NT (NN/64)   // 32 k-tiles

typedef _Float16 half_t;
typedef __attribute__((ext_vector_type(8))) _Float16 half8;
typedef __attribute__((ext_vector_type(4))) _Float16 half4;
typedef __attribute__((ext_vector_type(4))) float floatx4;

#define LOG2E 1.44269504088896f
#define EXP2_OFF 4.3280851f   // 3 * log2(e)

// async global->LDS, 16 B per lane; LDS dest must be wave-uniform base (+lane*16)
typedef const __attribute__((address_space(1))) unsigned int* gas_ptr;
typedef __attribute__((address_space(3))) unsigned int* las_ptr;
__device__ __forceinline__ void gld16(const half_t* g, half_t* l) {
  __builtin_amdgcn_global_load_lds((gas_ptr)g, (las_ptr)l, 16, 0, 0);
}

// ---------------------------------------------------------------------------
// fp32 -> fp16 convert (8 elems/thread)
// ---------------------------------------------------------------------------
__global__ __launch_bounds__(256) void cvt_kernel(
    const float* __restrict__ s, half_t* __restrict__ d, int n8) {
  int i = blockIdx.x * 256 + threadIdx.x;
  if (i < n8) {
    float4 a = ((const float4*)s)[i * 2], b = ((const float4*)s)[i * 2 + 1];
    half8 h;
    h[0] = (half_t)a.x; h[1] = (half_t)a.y; h[2] = (half_t)a.z; h[3] = (half_t)a.w;
    h[4] = (half_t)b.x; h[5] = (half_t)b.y; h[6] = (half_t)b.z; h[7] = (half_t)b.w;
    ((half8*)d)[i] = h;
  }
}

// mask -> EM = exp2(mask*log2e - off) fp16 table (multiplicative key mask)
__global__ __launch_bounds__(256) void em_kernel(
    const float* __restrict__ mask, half_t* __restrict__ EM, int n) {
  int i = blockIdx.x * 256 + threadIdx.x;
  if (i < n)
    EM[i] = (half_t)__builtin_amdgcn_exp2f(mask[i] * LOG2E - EXP2_OFF);
}

// ---------------------------------------------------------------------------
// Kernel 1: qkv = x @ W_qkv^T  (fp16 MFMA, 128x128 tile, BK=32, 4 waves)
// Fused epilogue: RoPE (+ q scale incl. log2e) -> Qh/Kh fp16 (B,H,N,D);
// V -> LDS transpose -> Vt fp16 (B,H,D,N).
// ---------------------------------------------------------------------------
__global__ __launch_bounds__(256) void qkv_mfma_kernel(
    const half_t* __restrict__ Ah,   // (16384, 512)
    const half_t* __restrict__ Bh,   // (1536, 512)
    const int*   __restrict__ ncp,
    half_t* __restrict__ Qh, half_t* __restrict__ Kh, half_t* __restrict__ Vt)
{
  __shared__ union {
    struct { half_t A[128 * 32]; half_t B[128 * 32]; } s;   // 16 KB
    half_t T[4][64 * 68];                                   // 34.8 KB (V epilogue)
  } sm;

  const int tid  = threadIdx.x;
  const int wave = tid >> 6, lane = tid & 63;
  const int L15  = lane & 15, quad = lane >> 4;
  const int wm = (wave & 1) * 64, wn = (wave >> 1) * 64;
  const int m0 = blockIdx.x * 128;
  const int f0 = blockIdx.y * 128;

  const int srow = lane >> 2;            // 0..15
  const int scolh = (lane & 3) * 8;      // half offset within row
  const half_t* Ag = Ah + (size_t)(m0 + wave * 16 + srow) * CC + scolh;
  const half_t* Bg = Bh + (size_t)(f0 + wave * 16 + srow) * CC + scolh;
  half_t* Al = &sm.s.A[(wave * 16) * 32];
  half_t* Bl = &sm.s.B[(wave * 16) * 32];

  floatx4 acc[4][4];
#pragma unroll
  for (int i = 0; i < 4; ++i)
#pragma unroll
    for (int j = 0; j < 4; ++j) acc[i][j] = (floatx4){0.f, 0.f, 0.f, 0.f};

  for (int k0 = 0; k0 < CC; k0 += 32) {
    __syncthreads();
    gld16(Ag + k0,            Al);
    gld16(Ag + k0 + 64 * CC,  Al + 64 * 32);
    gld16(Bg + k0,            Bl);
    gld16(Bg + k0 + 64 * CC,  Bl + 64 * 32);
    __syncthreads();
    half8 af[4], bf[4];
#pragma unroll
    for (int mi = 0; mi < 4; ++mi)
      af[mi] = *(const half8*)&sm.s.A[(wm + mi * 16 + L15) * 32 + quad * 8];
#pragma unroll
    for (int ni = 0; ni < 4; ++ni)
      bf[ni] = *(const half8*)&sm.s.B[(wn + ni * 16 + L15) * 32 + quad * 8];
#pragma unroll
    for (int mi = 0; mi < 4; ++mi)
#pragma unroll
      for (int ni = 0; ni < 4; ++ni)
        acc[mi][ni] = __builtin_amdgcn_mfma_f32_16x16x32_f16(af[mi], bf[ni], acc[mi][ni], 0, 0, 0);
  }

  const int which = f0 >> 9;         // block-uniform (128 | 512)
  const int b     = m0 >> 11;        // block-uniform
  const int n_base = (m0 & 2047) + wm;

  if (which < 2) {
    const int nc = *ncp;
    half_t* dst = which ? Kh : Qh;
    const float qscale = which ? 1.0f : (0.125f * LOG2E);
#pragma unroll
    for (int ni = 0; ni < 4; ++ni) {
      const int f = f0 + wn + ni * 16 + L15;
      const int h = (f >> 6) & 7;
      const int d = f & 63;
      const float invf = __powf(10000.0f, -(float)(d & ~1) * (1.0f / 64.0f));
      const float sgn = (d & 1) ? 1.0f : -1.0f;
#pragma unroll
      for (int mi = 0; mi < 4; ++mi)
#pragma unroll
        for (int r = 0; r < 4; ++r) {
          const int n = n_base + mi * 16 + quad * 4 + r;
          float v = acc[mi][ni][r];
          float p = __shfl_xor(v, 1, 64);   // RoPE partner (d ^ 1)
          if (n >= nc) {
            float sv, cv;
            __sincosf((float)(n - nc) * invf, &sv, &cv);
            v = v * cv + sgn * p * sv;
          }
          dst[(((size_t)(b * HH + h) * NN + n) << 6) + d] = (half_t)(v * qscale);
        }
    }
  } else {
    // V: per-wave 64x64 transpose through LDS -> (B,H,D,N)
    __syncthreads();   // all waves done reading sm.s (union overwrite)
#pragma unroll
    for (int ni = 0; ni < 4; ++ni)
#pragma unroll
      for (int mi = 0; mi < 4; ++mi)
#pragma unroll
        for (int r = 0; r < 4; ++r)
          sm.T[wave][(ni * 16 + L15) * 68 + mi * 16 + quad * 4 + r] = (half_t)acc[mi][ni][r];
    __syncthreads();
    const int h = ((f0 + wn) >> 6) & 7;
    const size_t gbase = ((size_t)(b * HH + h) * DD + lane) * NN + n_base;
#pragma unroll
    for (int c = 0; c < 8; ++c)
      *(half8*)(Vt + gbase + c * 8) = *(const half8*)&sm.T[wave][lane * 68 + c * 8];
  }
}

// ---------------------------------------------------------------------------
// Kernel 2: MFMA flash attention, S^T formulation, no K/V LDS staging, no
// __syncthreads.  R8 fixed the LDS race (same-type half4 accesses + explicit
// `s_waitcnt lgkmcnt(0)` with memory clobber); R9 restores latency hiding:
// K/EM fragments for tile kt+1 are double-buffered in VGPRs and issued
// mid-iteration (before the clobber, so they stay pinned early), V fragments
// for tile kt are issued at iteration top and consumed ~400 cyc later.
// ---------------------------------------------------------------------------
#define PP 72
__device__ __forceinline__ void flash_iter(
    int kt, int ktn,
    const half_t* __restrict__ Kt_base, const half_t* __restrict__ Vt_base,
    const half_t* __restrict__ EMb,
    half8 (&ka_cur)[4][2], half8 (&ka_nxt)[4][2],
    half4 (&em_cur)[4], half4 (&em_nxt)[4],
    half8 (&qa)[2][2], floatx4 (&oacc)[2][4], float (&l_part)[2],
    half_t* Pw, int L15, int quad)
{
  // V^T A-fragments for the CURRENT tile: A[m=d=sd*16+L15][k=key]
  half8 vb[4][2];
#pragma unroll
  for (int sd = 0; sd < 4; ++sd) {
    const half_t* vr = Vt_base + (size_t)(sd * 16 + L15) * NN + kt * 64 + quad * 8;
    vb[sd][0] = *(const half8*)(vr);
    vb[sd][1] = *(const half8*)(vr + 32);
  }

  // S^T = K Q^T per 16-key group; exp + P-store fused (keeps S short-lived).
  // Next-tile K fragments issued inside the loop to overlap with exp VALU.
#pragma unroll
  for (int s = 0; s < 4; ++s) {
    floatx4 S0 = {0.f, 0.f, 0.f, 0.f}, S1 = {0.f, 0.f, 0.f, 0.f};
    S0 = __builtin_amdgcn_mfma_f32_16x16x32_f16(ka_cur[s][0], qa[0][0], S0, 0, 0, 0);
    S0 = __builtin_amdgcn_mfma_f32_16x16x32_f16(ka_cur[s][1], qa[0][1], S0, 0, 0, 0);
    S1 = __builtin_amdgcn_mfma_f32_16x16x32_f16(ka_cur[s][0], qa[1][0], S1, 0, 0, 0);
    S1 = __builtin_amdgcn_mfma_f32_16x16x32_f16(ka_cur[s][1], qa[1][1], S1, 0, 0, 0);

    // prefetch next-tile K fragment for this s (ka_cur fully consumed above)
    const half_t* kr = Kt_base + (((size_t)ktn * 64 + s * 16 + L15) << 6) + quad * 8;
    ka_nxt[s][0] = *(const half8*)(kr);
    ka_nxt[s][1] = *(const half8*)(kr + 32);

    const float emf0 = (float)em_cur[s][0], emf1 = (float)em_cur[s][1];
    const float emf2 = (float)em_cur[s][2], emf3 = (float)em_cur[s][3];
    {
      float p0 = __builtin_amdgcn_exp2f(S0[0]) * emf0;
      float p1 = __builtin_amdgcn_exp2f(S0[1]) * emf1;
      float p2 = __builtin_amdgcn_exp2f(S0[2]) * emf2;
      float p3 = __builtin_amdgcn_exp2f(S0[3]) * emf3;
      l_part[0] += p0 + p1 + p2 + p3;
      half4 pv = {(half_t)p0, (half_t)p1, (half_t)p2, (half_t)p3};
      *(half4*)&Pw[(L15) * PP + s * 16 + quad * 4] = pv;
    }
    {
      float p0 = __builtin_amdgcn_exp2f(S1[0]) * emf0;
      float p1 = __builtin_amdgcn_exp2f(S1[1]) * emf1;
      float p2 = __builtin_amdgcn_exp2f(S1[2]) * emf2;
      float p3 = __builtin_amdgcn_exp2f(S1[3]) * emf3;
      l_part[1] += p0 + p1 + p2 + p3;
      half4 pv = {(half_t)p0, (half_t)p1, (half_t)p2, (half_t)p3};
      *(half4*)&Pw[(16 + L15) * PP + s * 16 + quad * 4] = pv;
    }
  }

  // prefetch next-tile EM
#pragma unroll
  for (int s = 0; s < 4; ++s)
    em_nxt[s] = *(const half4*)(EMb + ktn * 64 + s * 16 + quad * 4);

  // HW + compiler barrier: all wave DS writes complete before DS reads.
  __asm__ volatile("s_waitcnt lgkmcnt(0)" ::: "memory");

  // P B-fragments: B[n=q=L15][k=key]; half4 reads (same type as stores)
  half8 pa[2][2];
#pragma unroll
  for (int g = 0; g < 2; ++g)
#pragma unroll
    for (int c = 0; c < 2; ++c) {
      half4 lo = *(const half4*)&Pw[(g * 16 + L15) * PP + c * 32 + quad * 8];
      half4 hi = *(const half4*)&Pw[(g * 16 + L15) * PP + c * 32 + quad * 8 + 4];
      pa[g][c] = __builtin_shufflevector(lo, hi, 0, 1, 2, 3, 4, 5, 6, 7);
    }

  // O^T += V^T P^T
#pragma unroll
  for (int sd = 0; sd < 4; ++sd)
#pragma unroll
    for (int g = 0; g < 2; ++g) {
      oacc[g][sd] = __builtin_amdgcn_mfma_f32_16x16x32_f16(vb[sd][0], pa[g][0], oacc[g][sd], 0, 0, 0);
      oacc[g][sd] = __builtin_amdgcn_mfma_f32_16x16x32_f16(vb[sd][1], pa[g][1], oacc[g][sd], 0, 0, 0);
    }
}

__global__ __launch_bounds__(256, 3) void flash_mfma_kernel(
    const half_t* __restrict__ Qh,   // (B,H,N,D)  (q pre-scaled by 0.125*log2e)
    const half_t* __restrict__ Kh,   // (B,H,N,D)
    const half_t* __restrict__ Vt,   // (B,H,D,N)
    const half_t* __restrict__ EM,   // (B,N) fp16 multiplicative mask
    half_t* __restrict__ O)          // (B,N,C) fp16
{
  __shared__ half_t Pst[4][32 * PP];   // 18.4 KB, wave-private P tiles

  const int tid  = threadIdx.x;
  const int wave = tid >> 6;            // 0..3
  const int lane = tid & 63;
  const int L15  = lane & 15;
  const int quad = lane >> 4;

  // XCD-aware decode: blocks with the same head share blockIdx%8 (same XCD)
  const int bid  = blockIdx.x;          // 0..1023
  const int xcd  = bid & 7;
  const int slot = bid >> 3;            // 0..127
  const int qt   = slot & 15;           // 16 q-tiles of 128 rows
  const int head = (slot >> 4) * 8 + xcd;   // 0..63
  const int b    = head >> 3;
  const int h    = head & 7;

  const half_t* Kt_base = Kh + ((((size_t)b * HH + h) * NN) << 6);
  const half_t* Vt_base = Vt + ((((size_t)b * HH + h) * DD) * NN);
  const half_t* EMb     = EM + (size_t)b * NN;

  // Q fragments (B-frag: n=L15=q-row, k=quad*8+j=d), 2 g-sets of 16 rows
  half8 qa[2][2];
#pragma unroll
  for (int g = 0; g < 2; ++g) {
    const half_t* Qrow =
        Qh + ((((size_t)b * HH + h) * NN + qt * 128 + wave * 32 + g * 16 + L15) << 6);
    qa[g][0] = *(const half8*)(Qrow + quad * 8);
    qa[g][1] = *(const half8*)(Qrow + 32 + quad * 8);
  }

  floatx4 oacc[2][4];
#pragma unroll
  for (int g = 0; g < 2; ++g)
#pragma unroll
    for (int sd = 0; sd < 4; ++sd) oacc[g][sd] = (floatx4){0.f, 0.f, 0.f, 0.f};
  float l_part[2] = {0.f, 0.f};

  half_t* Pw = &Pst[wave][0];

  // preload tile 0 K fragments + EM
  half8 kaA[4][2], kaB[4][2];
  half4 emA[4], emB[4];
#pragma unroll
  for (int s = 0; s < 4; ++s) {
    const half_t* kr = Kt_base + (((size_t)s * 16 + L15) << 6) + quad * 8;
    kaA[s][0] = *(const half8*)(kr);
    kaA[s][1] = *(const half8*)(kr + 32);
    emA[s] = *(const half4*)(EMb + s * 16 + quad * 4);
  }

#pragma unroll 1
  for (int kt = 0; kt < NT; kt += 2) {
    flash_iter(kt, kt + 1, Kt_base, Vt_base, EMb,
               kaA, kaB, emA, emB, qa, oacc, l_part, Pw, L15, quad);
    flash_iter(kt + 1, (kt + 2) & (NT - 1), Kt_base, Vt_base, EMb,
               kaB, kaA, emB, emA, qa, oacc, l_part, Pw, L15, quad);
  }

  // cross-quad l reduction (keys split across quads; q-col = L15)
#pragma unroll
  for (int g = 0; g < 2; ++g) {
    l_part[g] += __shfl_xor(l_part[g], 16, 64);
    l_part[g] += __shfl_xor(l_part[g], 32, 64);
  }

  // epilogue: O^T layout: col q = L15, row d = sd*16 + quad*4 + r
#pragma unroll
  for (int g = 0; g < 2; ++g) {
    const float invl = 1.0f / l_part[g];
    const int row = qt * 128 + wave * 32 + g * 16 + L15;
    half_t* ob = O + (((size_t)b * NN + row) << 9) + (h << 6);
#pragma unroll
    for (int sd = 0; sd < 4; ++sd) {
      half4 o4 = {(half_t)(oacc[g][sd][0] * invl), (half_t)(oacc[g][sd][1] * invl),
                  (half_t)(oacc[g][sd][2] * invl), (half_t)(oacc[g][sd][3] * invl)};
      *(half4*)(ob + sd * 16 + quad * 4) = o4;
    }
  }
}

// ---------------------------------------------------------------------------
// Kernel 3: out = O @ W_proj^T + b_proj  (fp16 MFMA, fp32 out)
// ---------------------------------------------------------------------------
__global__ __launch_bounds__(256) void proj_mfma_kernel(
    const half_t* __restrict__ Ah,   // (16384, 512) fp16
    const half_t* __restrict__ Bh,   // (512, 512) fp16
    const float* __restrict__ bias,  // (512,)
    float* __restrict__ out)         // (16384, 512)
{
  __shared__ half_t As[128 * 32];
  __shared__ half_t Bs[128 * 32];

  const int tid  = threadIdx.x;
  const int wave = tid >> 6, lane = tid & 63;
  const int L15  = lane & 15, quad = lane >> 4;
  const int wm = (wave & 1) * 64, wn = (wave >> 1) * 64;
  const int m0 = blockIdx.x * 128;
  const int f0 = blockIdx.y * 128;

  const int srow = lane >> 2;
  const int scolh = (lane & 3) * 8;
  const half_t* Ag = Ah + (size_t)(m0 + wave * 16 + srow) * CC + scolh;
  const half_t* Bg = Bh + (size_t)(f0 + wave * 16 + srow) * CC + scolh;
  half_t* Al = &As[(wave * 16) * 32];
  half_t* Bl = &Bs[(wave * 16) * 32];

  floatx4 acc[4][4];
#pragma unroll
  for (int i = 0; i < 4; ++i)
#pragma unroll
    for (int j = 0; j < 4; ++j) acc[i][j] = (floatx4){0.f, 0.f, 0.f, 0.f};

  for (int k0 = 0; k0 < CC; k0 += 32) {
    __syncthreads();
    gld16(Ag + k0,           Al);
    gld16(Ag + k0 + 64 * CC, Al + 64 * 32);
    gld16(Bg + k0,           Bl);
    gld16(Bg + k0 + 64 * CC, Bl + 64 * 32);
    __syncthreads();
    half8 af[4], bf[4];
#pragma unroll
    for (int mi = 0; mi < 4; ++mi)
      af[mi] = *(const half8*)&As[(wm + mi * 16 + L15) * 32 + quad * 8];
#pragma unroll
    for (int ni = 0; ni < 4; ++ni)
      bf[ni] = *(const half8*)&Bs[(wn + ni * 16 + L15) * 32 + quad * 8];
#pragma unroll
    for (int mi = 0; mi < 4; ++mi)
#pragma unroll
      for (int ni = 0; ni < 4; ++ni)
        acc[mi][ni] = __builtin_amdgcn_mfma_f32_16x16x32_f16(af[mi], bf[ni], acc[mi][ni], 0, 0, 0);
  }

#pragma unroll
  for (int ni = 0; ni < 4; ++ni) {
    const int f = f0 + wn + ni * 16 + L15;
    const float bv = bias[f];
#pragma unroll
    for (int mi = 0; mi < 4; ++mi)
#pragma unroll
      for (int r = 0; r < 4; ++r)
        out[(size_t)(m0 + wm + mi * 16 + quad * 4 + r) * CC + f] = acc[mi][ni][r] + bv;
  }
}

// ---------------------------------------------------------------------------
extern "C" void kernel_launch(void* const* d_in, const int* in_sizes, int n_in,
                              void* d_out, int out_size, void* d_ws, size_t ws_size,
                              hipStream_t stream) {
  const float* x     = (const float*)d_in[0];
  const float* mask  = (const float*)d_in[1];
  const float* Wqkv  = (const float*)d_in[2];
  const float* Wproj = (const float*)d_in[3];
  const float* bproj = (const float*)d_in[4];
  const int*   ncp   = (const int*)d_in[5];
  float* out = (float*)d_out;

  const size_t per = (size_t)BB * HH * NN * DD;   // 8,388,608
  half_t* xh  = (half_t*)d_ws;
  half_t* Wqh = xh + (size_t)MM * CC;
  half_t* Wph = Wqh + (size_t)FF * CC;
  half_t* Qh  = Wph + (size_t)CC * CC;
  half_t* Kh  = Qh + per;
  half_t* Vt  = Kh + per;
  half_t* Oh  = Vt + per;
  half_t* EMt = Oh + (size_t)MM * CC;

  cvt_kernel<<<dim3(MM * CC / 8 / 256), 256, 0, stream>>>(x, xh, MM * CC / 8);
  cvt_kernel<<<dim3(FF * CC / 8 / 256), 256, 0, stream>>>(Wqkv, Wqh, FF * CC / 8);
  cvt_kernel<<<dim3(CC * CC / 8 / 256), 256, 0, stream>>>(Wproj, Wph, CC * CC / 8);
  em_kernel<<<dim3(MM / 256), 256, 0, stream>>>(mask, EMt, MM);

  qkv_mfma_kernel<<<dim3(MM / 128, FF / 128), 256, 0, stream>>>(xh, Wqh, ncp, Qh, Kh, Vt);
  flash_mfma_kernel<<<dim3(BB * HH * (NN / 128)), 256, 0, stream>>>(Qh, Kh, Vt, EMt, Oh);
  proj_mfma_kernel<<<dim3(MM / 128, CC / 128), 256, 0, stream>>>(Oh, Wph, bproj, out);
}

// Round 10
// 271.420 us; speedup vs baseline: 1.6550x; 1.6550x over previous
//
#include <hip/hip_runtime.h>
#include <cmath>

#define BB 8
#define NN 2048
#define CC 512
#define HH 8
#define DD 64
#define FF 1536
#define MM (BB*NN)   // 16384
#define NT (NN/64)   // 32 k-tiles

typedef _Float16 half_t;
typedef __attribute__((ext_vector_type(8))) _Float16 half8;
typedef __attribute__((ext_vector_type(4))) _Float16 half4;
typedef __attribute__((ext_vector_type(4))) float floatx4;

#define LOG2E 1.44269504088896f
#define EXP2_OFF 4.3280851f   // 3 * log2(e)

// async global->LDS, 16 B per lane; LDS dest must be wave-uniform base (+lane*16)
typedef const __attribute__((address_space(1))) unsigned int* gas_ptr;
typedef __attribute__((address_space(3))) unsigned int* las_ptr;
__device__ __forceinline__ void gld16(const half_t* g, half_t* l) {
  __builtin_amdgcn_global_load_lds((gas_ptr)g, (las_ptr)l, 16, 0, 0);
}

// ---------------------------------------------------------------------------
// fp32 -> fp16 convert (8 elems/thread)
// ---------------------------------------------------------------------------
__global__ __launch_bounds__(256) void cvt_kernel(
    const float* __restrict__ s, half_t* __restrict__ d, int n8) {
  int i = blockIdx.x * 256 + threadIdx.x;
  if (i < n8) {
    float4 a = ((const float4*)s)[i * 2], b = ((const float4*)s)[i * 2 + 1];
    half8 h;
    h[0] = (half_t)a.x; h[1] = (half_t)a.y; h[2] = (half_t)a.z; h[3] = (half_t)a.w;
    h[4] = (half_t)b.x; h[5] = (half_t)b.y; h[6] = (half_t)b.z; h[7] = (half_t)b.w;
    ((half8*)d)[i] = h;
  }
}

// mask -> EM = exp2(mask*log2e - off) fp16 table (multiplicative key mask)
__global__ __launch_bounds__(256) void em_kernel(
    const float* __restrict__ mask, half_t* __restrict__ EM, int n) {
  int i = blockIdx.x * 256 + threadIdx.x;
  if (i < n)
    EM[i] = (half_t)__builtin_amdgcn_exp2f(mask[i] * LOG2E - EXP2_OFF);
}

// ---------------------------------------------------------------------------
// Kernel 1: qkv = x @ W_qkv^T  (fp16 MFMA, 128x128 tile, BK=32, 4 waves)
// Fused epilogue: RoPE (+ q scale incl. log2e) -> Qh/Kh fp16 (B,H,N,D);
// V -> LDS transpose -> Vt fp16 (B,H,D,N).
// ---------------------------------------------------------------------------
__global__ __launch_bounds__(256) void qkv_mfma_kernel(
    const half_t* __restrict__ Ah,   // (16384, 512)
    const half_t* __restrict__ Bh,   // (1536, 512)
    const int*   __restrict__ ncp,
    half_t* __restrict__ Qh, half_t* __restrict__ Kh, half_t* __restrict__ Vt)
{
  __shared__ union {
    struct { half_t A[128 * 32]; half_t B[128 * 32]; } s;   // 16 KB
    half_t T[4][64 * 68];                                   // 34.8 KB (V epilogue)
  } sm;

  const int tid  = threadIdx.x;
  const int wave = tid >> 6, lane = tid & 63;
  const int L15  = lane & 15, quad = lane >> 4;
  const int wm = (wave & 1) * 64, wn = (wave >> 1) * 64;
  const int m0 = blockIdx.x * 128;
  const int f0 = blockIdx.y * 128;

  const int srow = lane >> 2;            // 0..15
  const int scolh = (lane & 3) * 8;      // half offset within row
  const half_t* Ag = Ah + (size_t)(m0 + wave * 16 + srow) * CC + scolh;
  const half_t* Bg = Bh + (size_t)(f0 + wave * 16 + srow) * CC + scolh;
  half_t* Al = &sm.s.A[(wave * 16) * 32];
  half_t* Bl = &sm.s.B[(wave * 16) * 32];

  floatx4 acc[4][4];
#pragma unroll
  for (int i = 0; i < 4; ++i)
#pragma unroll
    for (int j = 0; j < 4; ++j) acc[i][j] = (floatx4){0.f, 0.f, 0.f, 0.f};

  for (int k0 = 0; k0 < CC; k0 += 32) {
    __syncthreads();
    gld16(Ag + k0,            Al);
    gld16(Ag + k0 + 64 * CC,  Al + 64 * 32);
    gld16(Bg + k0,            Bl);
    gld16(Bg + k0 + 64 * CC,  Bl + 64 * 32);
    __syncthreads();
    half8 af[4], bf[4];
#pragma unroll
    for (int mi = 0; mi < 4; ++mi)
      af[mi] = *(const half8*)&sm.s.A[(wm + mi * 16 + L15) * 32 + quad * 8];
#pragma unroll
    for (int ni = 0; ni < 4; ++ni)
      bf[ni] = *(const half8*)&sm.s.B[(wn + ni * 16 + L15) * 32 + quad * 8];
#pragma unroll
    for (int mi = 0; mi < 4; ++mi)
#pragma unroll
      for (int ni = 0; ni < 4; ++ni)
        acc[mi][ni] = __builtin_amdgcn_mfma_f32_16x16x32_f16(af[mi], bf[ni], acc[mi][ni], 0, 0, 0);
  }

  const int which = f0 >> 9;         // block-uniform (128 | 512)
  const int b     = m0 >> 11;        // block-uniform
  const int n_base = (m0 & 2047) + wm;

  if (which < 2) {
    const int nc = *ncp;
    half_t* dst = which ? Kh : Qh;
    const float qscale = which ? 1.0f : (0.125f * LOG2E);
#pragma unroll
    for (int ni = 0; ni < 4; ++ni) {
      const int f = f0 + wn + ni * 16 + L15;
      const int h = (f >> 6) & 7;
      const int d = f & 63;
      const float invf = __powf(10000.0f, -(float)(d & ~1) * (1.0f / 64.0f));
      const float sgn = (d & 1) ? 1.0f : -1.0f;
#pragma unroll
      for (int mi = 0; mi < 4; ++mi)
#pragma unroll
        for (int r = 0; r < 4; ++r) {
          const int n = n_base + mi * 16 + quad * 4 + r;
          float v = acc[mi][ni][r];
          float p = __shfl_xor(v, 1, 64);   // RoPE partner (d ^ 1)
          if (n >= nc) {
            float sv, cv;
            __sincosf((float)(n - nc) * invf, &sv, &cv);
            v = v * cv + sgn * p * sv;
          }
          dst[(((size_t)(b * HH + h) * NN + n) << 6) + d] = (half_t)(v * qscale);
        }
    }
  } else {
    // V: per-wave 64x64 transpose through LDS -> (B,H,D,N)
    __syncthreads();   // all waves done reading sm.s (union overwrite)
#pragma unroll
    for (int ni = 0; ni < 4; ++ni)
#pragma unroll
      for (int mi = 0; mi < 4; ++mi)
#pragma unroll
        for (int r = 0; r < 4; ++r)
          sm.T[wave][(ni * 16 + L15) * 68 + mi * 16 + quad * 4 + r] = (half_t)acc[mi][ni][r];
    __syncthreads();
    const int h = ((f0 + wn) >> 6) & 7;
    const size_t gbase = ((size_t)(b * HH + h) * DD + lane) * NN + n_base;
#pragma unroll
    for (int c = 0; c < 8; ++c)
      *(half8*)(Vt + gbase + c * 8) = *(const half8*)&sm.T[wave][lane * 68 + c * 8];
  }
}

// ---------------------------------------------------------------------------
// Kernel 2: MFMA flash attention — R6's proven skeleton (LDS staging of K/V,
// two barriers, register prefetch of tile kt+1, no spills) + R8's verified
// S^T math:
//   S^T = mfma(A=K from LDS, B=Q): lane holds 4 consecutive KEYS -> P
//   round-trip is half4 writes + half4 reads in wave-private LDS.
//   P' = exp2(S^T)*EM[key] (fixed-offset softmax, multiplicative fp16 mask);
//   l = per-lane sum, one cross-quad shfl at the end.
//   O^T = mfma(A=V^T from LDS, B=P).
// All LDS strides = 72 halfs (144 B = 36 dwords = 4 banks mod 32): each
// 8-consecutive-lane group starts at bank 4*L15 -> perfect 32-bank tiling,
// near-zero conflicts for staging writes, K/V b128 reads, and P b64 ops.
// Explicit `s_waitcnt lgkmcnt(0)` + memory clobber pins the P write->read
// ordering (R7's race fix, verified in R8/R9).
// ---------------------------------------------------------------------------
#define KPAD 72
#define PP 72
__global__ __launch_bounds__(256, 4) void flash_mfma_kernel(
    const half_t* __restrict__ Qh,   // (B,H,N,D)  (q pre-scaled by 0.125*log2e)
    const half_t* __restrict__ Kh,   // (B,H,N,D)
    const half_t* __restrict__ Vt,   // (B,H,D,N)
    const half_t* __restrict__ EM,   // (B,N) fp16 multiplicative mask
    half_t* __restrict__ O)          // (B,N,C) fp16
{
  __shared__ half_t Ks[64 * KPAD];      // 9.2 KB  [key][d]
  __shared__ half_t Vs[64 * KPAD];      // 9.2 KB  [d][key]
  __shared__ half_t Pst[4][32 * PP];    // 18.4 KB wave-private P [q][key]

  const int tid  = threadIdx.x;
  const int wave = tid >> 6;            // 0..3
  const int lane = tid & 63;
  const int L15  = lane & 15;
  const int quad = lane >> 4;

  // XCD-aware decode: blocks with the same head share blockIdx%8 (same XCD)
  const int bid  = blockIdx.x;          // 0..1023
  const int xcd  = bid & 7;
  const int slot = bid >> 3;            // 0..127
  const int qt   = slot & 15;           // 16 q-tiles of 128 rows
  const int head = (slot >> 4) * 8 + xcd;   // 0..63
  const int b    = head >> 3;
  const int h    = head & 7;

  const half_t* Kt_base = Kh + ((((size_t)b * HH + h) * NN) << 6);
  const half_t* Vt_base = Vt + ((((size_t)b * HH + h) * DD) * NN);
  const half_t* EMb     = EM + (size_t)b * NN;

  // Q B-fragments (n=L15=q-row, k=quad*8+j=d), 2 g-sets of 16 rows
  half8 qa[2][2];
#pragma unroll
  for (int g = 0; g < 2; ++g) {
    const half_t* Qrow =
        Qh + ((((size_t)b * HH + h) * NN + qt * 128 + wave * 32 + g * 16 + L15) << 6);
    qa[g][0] = *(const half8*)(Qrow + quad * 8);
    qa[g][1] = *(const half8*)(Qrow + 32 + quad * 8);
  }

  floatx4 oacc[2][4];   // O^T: [g][sd], D[m=d][n=q]
#pragma unroll
  for (int g = 0; g < 2; ++g)
#pragma unroll
    for (int sd = 0; sd < 4; ++sd) oacc[g][sd] = (floatx4){0.f, 0.f, 0.f, 0.f};
  float l_part[2] = {0.f, 0.f};

  half_t* Pw = &Pst[wave][0];

  // staging: 256 threads cover 64 rows x 64 halfs with two half8 each
  const int sn = tid >> 3;            // 0..31
  const int sp = (tid & 7) * 8;       // half offset
  half8 kreg[2], vreg[2];
  half4 em_cur[4], em_nxt[4];
#define LOAD_KV(kt)                                                               \
  {                                                                               \
    kreg[0] = *(const half8*)(Kt_base + (((size_t)(kt) * 64 + sn) << 6) + sp);    \
    kreg[1] = *(const half8*)(Kt_base + (((size_t)(kt) * 64 + sn + 32) << 6) + sp); \
    vreg[0] = *(const half8*)(Vt_base + (size_t)sn * NN + (kt) * 64 + sp);        \
    vreg[1] = *(const half8*)(Vt_base + (size_t)(sn + 32) * NN + (kt) * 64 + sp); \
  }
#define LOAD_EM(kt, dstm)                                                         \
  {                                                                               \
    _Pragma("unroll")                                                             \
    for (int s = 0; s < 4; ++s)                                                   \
      dstm[s] = *(const half4*)(EMb + (kt) * 64 + s * 16 + quad * 4);             \
  }

  LOAD_KV(0)
  LOAD_EM(0, em_cur)

  for (int kt = 0; kt < NT; ++kt) {
    __syncthreads();   // prior-tile compute reads of Ks/Vs done
    *(half8*)&Ks[sn * KPAD + sp]        = kreg[0];
    *(half8*)&Ks[(sn + 32) * KPAD + sp] = kreg[1];
    *(half8*)&Vs[sn * KPAD + sp]        = vreg[0];
    *(half8*)&Vs[(sn + 32) * KPAD + sp] = vreg[1];
    __syncthreads();
    if (kt + 1 < NT) {
      LOAD_KV(kt + 1)            // prefetch overlaps compute
      LOAD_EM(kt + 1, em_nxt)
    }

    // S^T = K Q^T per 16-key group; exp + EM + P-store fused (S short-lived)
#pragma unroll
    for (int s = 0; s < 4; ++s) {
      half8 ka0 = *(const half8*)&Ks[(s * 16 + L15) * KPAD + quad * 8];
      half8 ka1 = *(const half8*)&Ks[(s * 16 + L15) * KPAD + 32 + quad * 8];
      floatx4 S0 = {0.f, 0.f, 0.f, 0.f}, S1 = {0.f, 0.f, 0.f, 0.f};
      S0 = __builtin_amdgcn_mfma_f32_16x16x32_f16(ka0, qa[0][0], S0, 0, 0, 0);
      S0 = __builtin_amdgcn_mfma_f32_16x16x32_f16(ka1, qa[0][1], S0, 0, 0, 0);
      S1 = __builtin_amdgcn_mfma_f32_16x16x32_f16(ka0, qa[1][0], S1, 0, 0, 0);
      S1 = __builtin_amdgcn_mfma_f32_16x16x32_f16(ka1, qa[1][1], S1, 0, 0, 0);

      const float e0 = (float)em_cur[s][0], e1 = (float)em_cur[s][1];
      const float e2 = (float)em_cur[s][2], e3 = (float)em_cur[s][3];
      {
        float p0 = __builtin_amdgcn_exp2f(S0[0]) * e0;
        float p1 = __builtin_amdgcn_exp2f(S0[1]) * e1;
        float p2 = __builtin_amdgcn_exp2f(S0[2]) * e2;
        float p3 = __builtin_amdgcn_exp2f(S0[3]) * e3;
        l_part[0] += p0 + p1 + p2 + p3;
        half4 pv = {(half_t)p0, (half_t)p1, (half_t)p2, (half_t)p3};
        *(half4*)&Pw[(L15) * PP + s * 16 + quad * 4] = pv;
      }
      {
        float p0 = __builtin_amdgcn_exp2f(S1[0]) * e0;
        float p1 = __builtin_amdgcn_exp2f(S1[1]) * e1;
        float p2 = __builtin_amdgcn_exp2f(S1[2]) * e2;
        float p3 = __builtin_amdgcn_exp2f(S1[3]) * e3;
        l_part[1] += p0 + p1 + p2 + p3;
        half4 pv = {(half_t)p0, (half_t)p1, (half_t)p2, (half_t)p3};
        *(half4*)&Pw[(16 + L15) * PP + s * 16 + quad * 4] = pv;
      }
    }

    // HW + compiler barrier: all wave DS writes complete before DS reads.
    __asm__ volatile("s_waitcnt lgkmcnt(0)" ::: "memory");

    // P B-fragments: B[n=q=L15][k=key]; half4 reads (same type as stores)
    half8 pa[2][2];
#pragma unroll
    for (int g = 0; g < 2; ++g)
#pragma unroll
      for (int c = 0; c < 2; ++c) {
        half4 lo = *(const half4*)&Pw[(g * 16 + L15) * PP + c * 32 + quad * 8];
        half4 hi = *(const half4*)&Pw[(g * 16 + L15) * PP + c * 32 + quad * 8 + 4];
        pa[g][c] = __builtin_shufflevector(lo, hi, 0, 1, 2, 3, 4, 5, 6, 7);
      }

    // O^T += V^T P^T  (A = V^T fragments from LDS Vs[d][key])
#pragma unroll
    for (int sd = 0; sd < 4; ++sd) {
      half8 vb0 = *(const half8*)&Vs[(sd * 16 + L15) * KPAD + quad * 8];
      half8 vb1 = *(const half8*)&Vs[(sd * 16 + L15) * KPAD + 32 + quad * 8];
#pragma unroll
      for (int g = 0; g < 2; ++g) {
        oacc[g][sd] = __builtin_amdgcn_mfma_f32_16x16x32_f16(vb0, pa[g][0], oacc[g][sd], 0, 0, 0);
        oacc[g][sd] = __builtin_amdgcn_mfma_f32_16x16x32_f16(vb1, pa[g][1], oacc[g][sd], 0, 0, 0);
      }
    }

#pragma unroll
    for (int s = 0; s < 4; ++s) em_cur[s] = em_nxt[s];
  }

  // cross-quad l reduction (keys split across quads; q-col = L15)
#pragma unroll
  for (int g = 0; g < 2; ++g) {
    l_part[g] += __shfl_xor(l_part[g], 16, 64);
    l_part[g] += __shfl_xor(l_part[g], 32, 64);
  }

  // epilogue: O^T layout: col q = L15, row d = sd*16 + quad*4 + r
#pragma unroll
  for (int g = 0; g < 2; ++g) {
    const float invl = 1.0f / l_part[g];
    const int row = qt * 128 + wave * 32 + g * 16 + L15;
    half_t* ob = O + (((size_t)b * NN + row) << 9) + (h << 6);
#pragma unroll
    for (int sd = 0; sd < 4; ++sd) {
      half4 o4 = {(half_t)(oacc[g][sd][0] * invl), (half_t)(oacc[g][sd][1] * invl),
                  (half_t)(oacc[g][sd][2] * invl), (half_t)(oacc[g][sd][3] * invl)};
      *(half4*)(ob + sd * 16 + quad * 4) = o4;
    }
  }
}

// ---------------------------------------------------------------------------
// Kernel 3: out = O @ W_proj^T + b_proj  (fp16 MFMA, fp32 out)
// ---------------------------------------------------------------------------
__global__ __launch_bounds__(256) void proj_mfma_kernel(
    const half_t* __restrict__ Ah,   // (16384, 512) fp16
    const half_t* __restrict__ Bh,   // (512, 512) fp16
    const float* __restrict__ bias,  // (512,)
    float* __restrict__ out)         // (16384, 512)
{
  __shared__ half_t As[128 * 32];
  __shared__ half_t Bs[128 * 32];

  const int tid  = threadIdx.x;
  const int wave = tid >> 6, lane = tid & 63;
  const int L15  = lane & 15, quad = lane >> 4;
  const int wm = (wave & 1) * 64, wn = (wave >> 1) * 64;
  const int m0 = blockIdx.x * 128;
  const int f0 = blockIdx.y * 128;

  const int srow = lane >> 2;
  const int scolh = (lane & 3) * 8;
  const half_t* Ag = Ah + (size_t)(m0 + wave * 16 + srow) * CC + scolh;
  const half_t* Bg = Bh + (size_t)(f0 + wave * 16 + srow) * CC + scolh;
  half_t* Al = &As[(wave * 16) * 32];
  half_t* Bl = &Bs[(wave * 16) * 32];

  floatx4 acc[4][4];
#pragma unroll
  for (int i = 0; i < 4; ++i)
#pragma unroll
    for (int j = 0; j < 4; ++j) acc[i][j] = (floatx4){0.f, 0.f, 0.f, 0.f};

  for (int k0 = 0; k0 < CC; k0 += 32) {
    __syncthreads();
    gld16(Ag + k0,           Al);
    gld16(Ag + k0 + 64 * CC, Al + 64 * 32);
    gld16(Bg + k0,           Bl);
    gld16(Bg + k0 + 64 * CC, Bl + 64 * 32);
    __syncthreads();
    half8 af[4], bf[4];
#pragma unroll
    for (int mi = 0; mi < 4; ++mi)
      af[mi] = *(const half8*)&As[(wm + mi * 16 + L15) * 32 + quad * 8];
#pragma unroll
    for (int ni = 0; ni < 4; ++ni)
      bf[ni] = *(const half8*)&Bs[(wn + ni * 16 + L15) * 32 + quad * 8];
#pragma unroll
    for (int mi = 0; mi < 4; ++mi)
#pragma unroll
      for (int ni = 0; ni < 4; ++ni)
        acc[mi][ni] = __builtin_amdgcn_mfma_f32_16x16x32_f16(af[mi], bf[ni], acc[mi][ni], 0, 0, 0);
  }

#pragma unroll
  for (int ni = 0; ni < 4; ++ni) {
    const int f = f0 + wn + ni * 16 + L15;
    const float bv = bias[f];
#pragma unroll
    for (int mi = 0; mi < 4; ++mi)
#pragma unroll
      for (int r = 0; r < 4; ++r)
        out[(size_t)(m0 + wm + mi * 16 + quad * 4 + r) * CC + f] = acc[mi][ni][r] + bv;
  }
}

// ---------------------------------------------------------------------------
extern "C" void kernel_launch(void* const* d_in, const int* in_sizes, int n_in,
                              void* d_out, int out_size, void* d_ws, size_t ws_size,
                              hipStream_t stream) {
  const float* x     = (const float*)d_in[0];
  const float* mask  = (const float*)d_in[1];
  const float* Wqkv  = (const float*)d_in[2];
  const float* Wproj = (const float*)d_in[3];
  const float* bproj = (const float*)d_in[4];
  const int*   ncp   = (const int*)d_in[5];
  float* out = (float*)d_out;

  const size_t per = (size_t)BB * HH * NN * DD;   // 8,388,608
  half_t* xh  = (half_t*)d_ws;
  half_t* Wqh = xh + (size_t)MM * CC;
  half_t* Wph = Wqh + (size_t)FF * CC;
  half_t* Qh  = Wph + (size_t)CC * CC;
  half_t* Kh  = Qh + per;
  half_t* Vt  = Kh + per;
  half_t* Oh  = Vt + per;
  half_t* EMt = Oh + (size_t)MM * CC;

  cvt_kernel<<<dim3(MM * CC / 8 / 256), 256, 0, stream>>>(x, xh, MM * CC / 8);
  cvt_kernel<<<dim3(FF * CC / 8 / 256), 256, 0, stream>>>(Wqkv, Wqh, FF * CC / 8);
  cvt_kernel<<<dim3(CC * CC / 8 / 256), 256, 0, stream>>>(Wproj, Wph, CC * CC / 8);
  em_kernel<<<dim3(MM / 256), 256, 0, stream>>>(mask, EMt, MM);

  qkv_mfma_kernel<<<dim3(MM / 128, FF / 128), 256, 0, stream>>>(xh, Wqh, ncp, Qh, Kh, Vt);
  flash_mfma_kernel<<<dim3(BB * HH * (NN / 128)), 256, 0, stream>>>(Qh, Kh, Vt, EMt, Oh);
  proj_mfma_kernel<<<dim3(MM / 128, CC / 128), 256, 0, stream>>>(Oh, Wph, bproj, out);
}